// Round 14
// baseline (183.768 us; speedup 1.0000x reference)
//
#include <hip/hip_runtime.h>

typedef float f32x4 __attribute__((ext_vector_type(4)));
typedef float f32x16 __attribute__((ext_vector_type(16)));
typedef __bf16 bf16x8 __attribute__((ext_vector_type(8)));
typedef __bf16 bf16x4 __attribute__((ext_vector_type(4)));
typedef __bf16 bf16x2 __attribute__((ext_vector_type(2)));
typedef unsigned short us4 __attribute__((ext_vector_type(4)));

#define DEV __device__ __forceinline__

DEV unsigned short f2bf(float f) {
  union { float f; unsigned int u; } v; v.f = f;
  unsigned int u = v.u;
  return (unsigned short)((u + 0x7FFFu + ((u >> 16) & 1u)) >> 16);
}

typedef const __attribute__((address_space(1))) void* gvp;
typedef __attribute__((address_space(3))) void* lvp;

DEV void gll16(const void* g, void* l) {
  __builtin_amdgcn_global_load_lds((gvp)g, (lvp)l, 16, 0, 0);
}

DEV float fexp2(float x) { return __builtin_amdgcn_exp2f(x); }

DEV void plswap(unsigned& a, unsigned& b) {
  asm("v_permlane32_swap_b32 %0, %1" : "+v"(a), "+v"(b));
}
DEV float xhalf_sum(float v) {
  union { float f; unsigned u; } a, b;
  a.f = v; b.f = v;
  plswap(a.u, b.u);
  return a.f + b.f;
}

// ---------------- fused pre: convert fp32->bf16 + 4x weight transpose ----------------
__global__ void k_pre(const float* __restrict__ x, unsigned short* __restrict__ xb,
                      const float* __restrict__ w0, const float* __restrict__ w1,
                      const float* __restrict__ w2, const float* __restrict__ w3,
                      unsigned short* __restrict__ o0, unsigned short* __restrict__ o1,
                      unsigned short* __restrict__ o2, unsigned short* __restrict__ o3) {
  __shared__ float tile[32][33];
  const int bid = blockIdx.x;
  const int tid = threadIdx.x;
  if (bid < 8192) {
    int i = bid * 256 + tid;
    float4 v = ((const float4*)x)[i];
    us4 o = { f2bf(v.x), f2bf(v.y), f2bf(v.z), f2bf(v.w) };
    ((us4*)xb)[i] = o;
    return;
  }
  int t = bid - 8192;
  const int z = t >> 10;
  t &= 1023;
  const float* in = (z == 0) ? w0 : (z == 1) ? w1 : (z == 2) ? w2 : w3;
  unsigned short* out = (z == 0) ? o0 : (z == 1) ? o1 : (z == 2) ? o2 : o3;
  const int bx = (t & 31) * 32, by = (t >> 5) * 32;
  const int tx = tid & 31, ty = tid >> 5;
#pragma unroll
  for (int r = 0; r < 4; ++r)
    tile[ty + r * 8][tx] = in[(size_t)(by + ty + r * 8) * 1024 + bx + tx];
  __syncthreads();
#pragma unroll
  for (int r = 0; r < 4; ++r)
    out[(size_t)(bx + ty + r * 8) * 1024 + by + tx] = f2bf(tile[tx][ty + r * 8]);
}

// ---------------- fused QKV projection GEMM (z: 0=q, 1=k, 2=v^T) ----------------
__global__ void k_gemm_qkv(const unsigned short* __restrict__ xb,
                           const unsigned short* __restrict__ wqt,
                           const unsigned short* __restrict__ wkt,
                           const unsigned short* __restrict__ wvt,
                           const float* __restrict__ bq, const float* __restrict__ bk,
                           const float* __restrict__ bv,
                           unsigned short* __restrict__ qb, unsigned short* __restrict__ kb,
                           unsigned short* __restrict__ vtb) {
  __shared__ unsigned short SM[2][128 * 64];
  unsigned short* As = SM[0];
  unsigned short* Bs = SM[1];
  const int tid = threadIdx.x;
  const int lane = tid & 63;
  const int wave = tid >> 6;
  const int l15 = lane & 15;
  const int lq  = lane >> 4;
  const int wm = wave >> 1, wn = wave & 1;
  const int z = blockIdx.z;

  const unsigned short* A;
  const unsigned short* Bt;
  int mbase, nbase;
  if (z == 2) { A = wvt; Bt = xb; mbase = blockIdx.y * 128; nbase = blockIdx.x * 128; }
  else        { A = xb; Bt = z ? wkt : wqt; mbase = blockIdx.x * 128; nbase = blockIdx.y * 128; }

  f32x4 acc[4][4] = {};

  for (int kt = 0; kt < 1024; kt += 64) {
    __syncthreads();
#pragma unroll
    for (int c = 0; c < 4; ++c) {
      int e = (c * 256 + tid) * 8;
      int row = e >> 6;
      int o2 = (e * 2) ^ ((row & 7) << 4);
      int col = (o2 >> 1) & 63;
      gll16(A + (size_t)(mbase + row) * 1024 + kt + col,
            As + (c * 256 + (tid & ~63)) * 8);
      gll16(Bt + (size_t)(nbase + row) * 1024 + kt + col,
            Bs + (c * 256 + (tid & ~63)) * 8);
    }
    __syncthreads();
#pragma unroll
    for (int ks = 0; ks < 2; ++ks) {
      bf16x8 af[4], bfv[4];
#pragma unroll
      for (int i = 0; i < 4; ++i) {
        int row = wm * 64 + i * 16 + l15;
        int off = row * 128 + ((((ks << 2) | lq) ^ (row & 7)) << 4);
        af[i] = *(const bf16x8*)((const char*)As + off);
      }
#pragma unroll
      for (int j = 0; j < 4; ++j) {
        int row = wn * 64 + j * 16 + l15;
        int off = row * 128 + ((((ks << 2) | lq) ^ (row & 7)) << 4);
        bfv[j] = *(const bf16x8*)((const char*)Bs + off);
      }
#pragma unroll
      for (int i = 0; i < 4; ++i)
#pragma unroll
        for (int j = 0; j < 4; ++j)
          acc[i][j] = __builtin_amdgcn_mfma_f32_16x16x32_bf16(bfv[j], af[i], acc[i][j], 0, 0, 0);
    }
  }

  const float scale = (z == 0) ? 0.18033688011112042f : 1.0f;
  const float* bias = (z == 0) ? bq : (z == 1) ? bk : bv;
  unsigned short* outp = (z == 0) ? qb : (z == 1) ? kb : vtb;

  float4 bj[4];
  if (z < 2) {
#pragma unroll
    for (int j = 0; j < 4; ++j)
      bj[j] = *(const float4*)&bias[nbase + wn * 64 + j * 16 + lq * 4];
  }

  __syncthreads();
  char* T = (char*)SM;
#pragma unroll
  for (int i = 0; i < 4; ++i) {
    const int miL = wm * 64 + i * 16 + l15;
    const int sw = (miL & 7) << 4;
    const float bm = (z == 2) ? bias[mbase + miL] : 0.f;
#pragma unroll
    for (int j = 0; j < 4; ++j) {
      const int nj2 = (wn * 64 + j * 16 + lq * 4) * 2;
      bf16x4 p;
#pragma unroll
      for (int r = 0; r < 4; ++r) {
        float v = acc[i][j][r];
        v = (z < 2) ? (v + ((const float*)&bj[j])[r]) * scale : (v + bm);
        p[r] = (__bf16)v;
      }
      *(bf16x4*)(T + miL * 256 + (nj2 ^ sw)) = p;
    }
  }
  __syncthreads();

#pragma unroll
  for (int c = 0; c < 8; ++c) {
    const int lin = c * 256 + tid;
    const int row = lin >> 4;
    const int s16 = lin & 15;
    bf16x8 vv = *(const bf16x8*)(T + row * 256 + ((s16 * 16) ^ ((row & 7) << 4)));
    const int mi = mbase + row;
    const int nj = nbase + s16 * 8;
    size_t gaddr;
    if (z < 2) {
      gaddr = (((size_t)((mi >> 11) * 16 + (nj >> 6)) * 2048 + (mi & 2047)) << 6) + (nj & 63);
    } else {
      gaddr = ((size_t)(((nj >> 11) * 16 + (mi >> 6)) * 64 + (mi & 63))) * 2048 + (nj & 2047);
    }
    *(bf16x8*)(outp + gaddr) = vv;
  }
}

// ---------------- output-projection GEMM: y(bf16) = ctx*Wo + bo + x ----------------
__global__ void k_gemm_out(const unsigned short* __restrict__ A,
                           const unsigned short* __restrict__ Bt,
                           const float* __restrict__ bias,
                           unsigned short* __restrict__ yb,
                           const unsigned short* __restrict__ xres) {
  __shared__ unsigned short SMo[2][128 * 64];
  unsigned short* As = SMo[0];
  unsigned short* Bs = SMo[1];
  const int tid = threadIdx.x;
  const int lane = tid & 63;
  const int wave = tid >> 6;
  const int l15 = lane & 15;
  const int lq  = lane >> 4;
  const int wm = wave >> 1, wn = wave & 1;
  const int mbase = blockIdx.x * 128;
  const int nbase = blockIdx.y * 128;

  f32x4 acc[4][4] = {};

  for (int kt = 0; kt < 1024; kt += 64) {
    __syncthreads();
#pragma unroll
    for (int c = 0; c < 4; ++c) {
      int e = (c * 256 + tid) * 8;
      int row = e >> 6;
      int o2 = (e * 2) ^ ((row & 7) << 4);
      int col = (o2 >> 1) & 63;
      gll16(A + (size_t)(mbase + row) * 1024 + kt + col,
            As + (c * 256 + (tid & ~63)) * 8);
      gll16(Bt + (size_t)(nbase + row) * 1024 + kt + col,
            Bs + (c * 256 + (tid & ~63)) * 8);
    }
    __syncthreads();
#pragma unroll
    for (int ks = 0; ks < 2; ++ks) {
      bf16x8 af[4], bfv[4];
#pragma unroll
      for (int i = 0; i < 4; ++i) {
        int row = wm * 64 + i * 16 + l15;
        int off = row * 128 + ((((ks << 2) | lq) ^ (row & 7)) << 4);
        af[i] = *(const bf16x8*)((const char*)As + off);
      }
#pragma unroll
      for (int j = 0; j < 4; ++j) {
        int row = wn * 64 + j * 16 + l15;
        int off = row * 128 + ((((ks << 2) | lq) ^ (row & 7)) << 4);
        bfv[j] = *(const bf16x8*)((const char*)Bs + off);
      }
#pragma unroll
      for (int i = 0; i < 4; ++i)
#pragma unroll
        for (int j = 0; j < 4; ++j)
          acc[i][j] = __builtin_amdgcn_mfma_f32_16x16x32_bf16(bfv[j], af[i], acc[i][j], 0, 0, 0);
    }
  }

  float4 bj[4];
#pragma unroll
  for (int j = 0; j < 4; ++j)
    bj[j] = *(const float4*)&bias[nbase + wn * 64 + j * 16 + lq * 4];

  __syncthreads();
  char* T = (char*)SMo;
#pragma unroll
  for (int i = 0; i < 4; ++i) {
    const int miL = wm * 64 + i * 16 + l15;
    const int sw = (miL & 7) << 4;
#pragma unroll
    for (int j = 0; j < 4; ++j) {
      const int nj2 = (wn * 64 + j * 16 + lq * 4) * 2;
      bf16x4 p;
#pragma unroll
      for (int r = 0; r < 4; ++r)
        p[r] = (__bf16)(acc[i][j][r] + ((const float*)&bj[j])[r]);
      *(bf16x4*)(T + miL * 256 + (nj2 ^ sw)) = p;
    }
  }
  __syncthreads();

#pragma unroll
  for (int c = 0; c < 8; ++c) {
    const int lin = c * 256 + tid;
    const int row = lin >> 4;
    const int s16 = lin & 15;
    bf16x8 vv = *(const bf16x8*)(T + row * 256 + ((s16 * 16) ^ ((row & 7) << 4)));
    const size_t g = (size_t)(mbase + row) * 1024 + nbase + s16 * 8;
    bf16x8 xv = *(const bf16x8*)(xres + g);
    bf16x8 ov;
#pragma unroll
    for (int e = 0; e < 8; ++e)
      ov[e] = (__bf16)((float)vv[e] + (float)xv[e]);
    *(bf16x8*)(yb + g) = ov;
  }
}

// ---------------- flash attention v11: counted-vmcnt barriers (K 3-deep, V 2-deep) ----------------
// q,k: [B,H,S,64] bf16 (q pre-scaled by 0.125*log2e); vt: [B,H,64,S] bf16
// ctx out: [B,S,H,64] bf16.  QBLK=128, 4 waves x 32 q, KVBLK=64, 32x32x16 mfma.
// Per-iter issue order: V(t+1) then K(t+2); barrier waits vmcnt(2) (K(t+2) stays
// in flight across the barrier — no drain-to-0 in the main loop).  LDS = 40 KB
// (3x8KB K ring + 2x8KB V ring) keeps 4 blocks/CU.
__global__ __launch_bounds__(256, 4) void k_attn(const unsigned short* __restrict__ q,
                       const unsigned short* __restrict__ k,
                       const unsigned short* __restrict__ vt,
                       unsigned short* __restrict__ ctx) {
  __shared__ unsigned short KL[3][64 * 64];   // 24 KB K ring
  __shared__ unsigned short VL[2][64 * 64];   // 16 KB V ring

  const int tid = threadIdx.x;
  const int lane = tid & 63;
  const int wave = tid >> 6;
  const int l31 = lane & 31;
  const int l5 = lane >> 5;
  const int prl = l31 >> 1;
  const int b3  = (l31 & 1) << 3;

  const int bid = blockIdx.x;
  const int swz = (bid & 7) * 128 + (bid >> 3);
  const int bh = swz >> 4;
  const int qtile = swz & 15;
  const int qbase = qtile * 128;
  const size_t sl = (size_t)bh << 17;

  const int qrow = qbase + wave * 32 + l31;
  bf16x8 qreg[4];
#pragma unroll
  for (int ds = 0; ds < 4; ++ds)
    qreg[ds] = *(const bf16x8*)(q + sl + (size_t)qrow * 64 + ds * 16 + l5 * 8);

  // inverse-swizzled staging ([32][256B] pair-interleaved layout, round-12 proven)
#define STAGE_K(DST, TT) do {                                                  \
    const int kvb_ = (TT) * 64;                                                \
    _Pragma("unroll")                                                          \
    for (int c = 0; c < 2; ++c) {                                              \
      int ci = c * 256 + tid;                                                  \
      int pr_ = ci >> 4;                                                       \
      int u_ = (ci & 15) ^ (pr_ & 15);                                         \
      int lrow_ = pr_ * 2 + (u_ >> 3);                                         \
      int lc_ = u_ & 7;                                                        \
      gll16(k + sl + (size_t)(kvb_ + lrow_) * 64 + lc_ * 8,                    \
            (DST) + (c * 256 + (tid & ~63)) * 8);                              \
    }                                                                          \
  } while (0)
#define STAGE_V(DST, TT) do {                                                  \
    const int kvb_ = (TT) * 64;                                                \
    _Pragma("unroll")                                                          \
    for (int c = 0; c < 2; ++c) {                                              \
      int ci = c * 256 + tid;                                                  \
      int pr_ = ci >> 4;                                                       \
      int u_ = (ci & 15) ^ (pr_ & 15);                                         \
      int lrow_ = pr_ * 2 + (u_ >> 3);                                         \
      int lc_ = u_ & 7;                                                        \
      gll16(vt + sl + (size_t)lrow_ * 2048 + kvb_ + lc_ * 8,                   \
            (DST) + (c * 256 + (tid & ~63)) * 8);                              \
    }                                                                          \
  } while (0)

  // prologue issue order (oldest->newest): K0, V0, K1
  STAGE_K(KL[0], 0);
  STAGE_V(VL[0], 0);
  STAGE_K(KL[1], 1);

  f32x16 acc0 = {}, acc1 = {};
  float lrow = 0.f;

  for (int t = 0; t < 32; ++t) {
    // barrier with counted wait: completes K(t),V(t); K(t+1) remains in flight
    asm volatile("s_waitcnt vmcnt(2)" ::: "memory");
    __builtin_amdgcn_s_barrier();

    const char* Ksc = (const char*)KL[t % 3];
    const char* Vtc = (const char*)VL[t & 1];

    // ---- phase 1: K fragments + QK^T
    bf16x8 kf0[4], kf1[4];
#pragma unroll
    for (int ds = 0; ds < 4; ++ds) {
      int sc = (b3 | (2 * ds + l5)) ^ prl;
      kf0[ds] = *(const bf16x8*)(Ksc + prl * 256 + sc * 16);
      kf1[ds] = *(const bf16x8*)(Ksc + 4096 + prl * 256 + sc * 16);
    }
    f32x16 s0 = {}, s1 = {};
    __builtin_amdgcn_s_setprio(1);
#pragma unroll
    for (int ds = 0; ds < 4; ++ds)
      s0 = __builtin_amdgcn_mfma_f32_32x32x16_bf16(kf0[ds], qreg[ds], s0, 0, 0, 0);
#pragma unroll
    for (int ds = 0; ds < 4; ++ds)
      s1 = __builtin_amdgcn_mfma_f32_32x32x16_bf16(kf1[ds], qreg[ds], s1, 0, 0, 0);
    __builtin_amdgcn_s_setprio(0);

    // issue V(t+1) (clamped tail keeps vmcnt accounting uniform; target unread)
    {
      const int tv = (t + 1 < 32) ? t + 1 : 31;
      STAGE_V(VL[(t + 1) & 1], tv);
    }
    __builtin_amdgcn_sched_barrier(0);

    // ---- phase 2: softmax (no max tracking)
    unsigned pk0[8], pk1[8];
    float r0s = 0.f, r1s = 0.f, r2s = 0.f, r3s = 0.f;
#pragma unroll
    for (int m = 0; m < 8; ++m) {
      float a0 = fexp2(s0[2 * m]), a1 = fexp2(s0[2 * m + 1]);
      float b0 = fexp2(s1[2 * m]), b1 = fexp2(s1[2 * m + 1]);
      r0s += a0; r1s += a1; r2s += b0; r3s += b1;
      union { bf16x2 v; unsigned u; } ua, ub;
      ua.v = bf16x2{ (__bf16)a0, (__bf16)a1 };
      ub.v = bf16x2{ (__bf16)b0, (__bf16)b1 };
      pk0[m] = ua.u; pk1[m] = ub.u;
    }
    lrow += (r0s + r1s) + (r2s + r3s);
    __builtin_amdgcn_sched_barrier(0);

    // ---- phase 3: V fragments + PV
    bf16x8 av0[4], av1[4];
#pragma unroll
    for (int kvg = 0; kvg < 4; ++kvg) {
      int sc = (b3 | (2 * kvg + l5)) ^ prl;
      av0[kvg] = *(const bf16x8*)(Vtc + prl * 256 + sc * 16);
      av1[kvg] = *(const bf16x8*)(Vtc + 4096 + prl * 256 + sc * 16);
    }
    __builtin_amdgcn_s_setprio(1);
#pragma unroll
    for (int kvh = 0; kvh < 2; ++kvh) {
      unsigned* pk = kvh ? pk1 : pk0;
#pragma unroll
      for (int g = 0; g < 2; ++g) {
        unsigned a0_ = pk[4 * g],     b0_ = pk[4 * g + 2];
        unsigned a1_ = pk[4 * g + 1], b1_ = pk[4 * g + 3];
        plswap(a0_, b0_);
        plswap(a1_, b1_);
        union { unsigned u[4]; bf16x8 v; } pf;
        pf.u[0] = a0_; pf.u[1] = a1_; pf.u[2] = b0_; pf.u[3] = b1_;
        const int kvg = 2 * kvh + g;
        acc0 = __builtin_amdgcn_mfma_f32_32x32x16_bf16(av0[kvg], pf.v, acc0, 0, 0, 0);
        acc1 = __builtin_amdgcn_mfma_f32_32x32x16_bf16(av1[kvg], pf.v, acc1, 0, 0, 0);
      }
    }
    __builtin_amdgcn_s_setprio(0);

    // issue K(t+2) (after V(t+1) in program order — vmcnt age ordering)
    {
      const int tk = (t + 2 < 32) ? t + 2 : 31;
      STAGE_K(KL[(t + 2) % 3], tk);
    }
  }

  const float inv = 1.f / xhalf_sum(lrow);

  __syncthreads();   // full drain before LDS reuse
  unsigned short* TR = (unsigned short*)KL;   // 16 KB epilogue scratch
  const int qloc = wave * 32 + l31;
  const int swq = (qloc & 7) << 4;
#pragma unroll
  for (int dh = 0; dh < 2; ++dh) {
    const f32x16& ac = dh ? acc1 : acc0;
#pragma unroll
    for (int g3 = 0; g3 < 4; ++g3) {
      bf16x4 o4 = { (__bf16)(ac[4 * g3] * inv), (__bf16)(ac[4 * g3 + 1] * inv),
                    (__bf16)(ac[4 * g3 + 2] * inv), (__bf16)(ac[4 * g3 + 3] * inv) };
      *(bf16x4*)((char*)TR + qloc * 128 + ((dh * 64 + g3 * 16 + l5 * 8) ^ swq)) = o4;
    }
  }
  __syncthreads();

  const int b = bh >> 4, h = bh & 15;
  {
    int row = tid >> 1, half = tid & 1;
    int sw = (row & 7) << 4;
    unsigned short* gdst = ctx + (size_t)(b * 2048 + qbase + row) * 1024 + h * 64 + half * 32;
#pragma unroll
    for (int i = 0; i < 4; ++i) {
      bf16x8 vv = *(const bf16x8*)((const char*)TR + row * 128 + ((half * 64 + i * 16) ^ sw));
      *(bf16x8*)(gdst + i * 8) = vv;
    }
  }
#undef STAGE_K
#undef STAGE_V
}

// ---------------- LayerNorm over D=1024, bf16 input ----------------
__global__ void k_ln(const unsigned short* __restrict__ y, const float* __restrict__ gamma,
                     const float* __restrict__ beta, float* __restrict__ out) {
  const int row = blockIdx.x;
  const int tid = threadIdx.x;
  const bf16x4 v4 = *(const bf16x4*)(y + (size_t)row * 1024 + tid * 4);
  float v0 = (float)v4[0], v1 = (float)v4[1], v2 = (float)v4[2], v3 = (float)v4[3];
  float sum = v0 + v1 + v2 + v3;
  float sq = v0 * v0 + v1 * v1 + v2 * v2 + v3 * v3;
#pragma unroll
  for (int m = 1; m <= 32; m <<= 1) {
    sum += __shfl_xor(sum, m);
    sq  += __shfl_xor(sq, m);
  }
  __shared__ float s1[4], s2[4];
  const int wv = tid >> 6, lane = tid & 63;
  if (lane == 0) { s1[wv] = sum; s2[wv] = sq; }
  __syncthreads();
  sum = s1[0] + s1[1] + s1[2] + s1[3];
  sq  = s2[0] + s2[1] + s2[2] + s2[3];
  const float mu = sum * (1.f / 1024.f);
  const float rs = rsqrtf(sq * (1.f / 1024.f) - mu * mu + 1e-3f);
  const float4 g  = ((const float4*)gamma)[tid];
  const float4 bb = ((const float4*)beta)[tid];
  float4 o;
  o.x = (v0 - mu) * rs * g.x + bb.x;
  o.y = (v1 - mu) * rs * g.y + bb.y;
  o.z = (v2 - mu) * rs * g.z + bb.z;
  o.w = (v3 - mu) * rs * g.w + bb.w;
  ((float4*)(out + (size_t)row * 1024))[tid] = o;
}

extern "C" void kernel_launch(void* const* d_in, const int* in_sizes, int n_in,
                              void* d_out, int out_size, void* d_ws, size_t ws_size,
                              hipStream_t stream) {
  const float* x  = (const float*)d_in[0];
  const float* Wq = (const float*)d_in[1];
  const float* bq = (const float*)d_in[2];
  const float* Wk = (const float*)d_in[3];
  const float* bk = (const float*)d_in[4];
  const float* Wv = (const float*)d_in[5];
  const float* bv = (const float*)d_in[6];
  const float* Wo = (const float*)d_in[7];
  const float* bo = (const float*)d_in[8];
  const float* gamma = (const float*)d_in[9];
  const float* beta  = (const float*)d_in[10];
  float* out = (float*)d_out;

  char* ws = (char*)d_ws;
  const size_t MB = 1024 * 1024;
  unsigned short* xb  = (unsigned short*)(ws);            // 16MB  x bf16 [8192][1024]
  unsigned short* wqt = (unsigned short*)(ws + 16 * MB);  // 2MB   Wq^T bf16
  unsigned short* wkt = (unsigned short*)(ws + 18 * MB);
  unsigned short* wvt = (unsigned short*)(ws + 20 * MB);
  unsigned short* wot = (unsigned short*)(ws + 22 * MB);
  unsigned short* qb  = (unsigned short*)(ws + 24 * MB);  // 16MB  q [B,H,S,64]
  unsigned short* kb  = (unsigned short*)(ws + 40 * MB);  // 16MB  k [B,H,S,64]
  unsigned short* vtb = (unsigned short*)(ws + 56 * MB);  // 16MB  v^T [B,H,64,S]
  unsigned short* ctx = (unsigned short*)(ws + 72 * MB);  // 16MB  ctx [B,S,H,64]
  unsigned short* yb  = (unsigned short*)(ws + 24 * MB);  // 16MB  y bf16, aliases qb

  k_pre<<<12288, 256, 0, stream>>>(x, xb, Wq, Wk, Wv, Wo, wqt, wkt, wvt, wot);

  // q = (x Wq + bq)*0.125*log2e ; k = x Wk + bk ; v^T = Wv^T x^T — one launch
  k_gemm_qkv<<<dim3(64, 8, 3), 256, 0, stream>>>(xb, wqt, wkt, wvt, bq, bk, bv, qb, kb, vtb);

  k_attn<<<1024, 256, 0, stream>>>(qb, kb, vtb, ctx);

  // y = ctx Wo + bo + x  (bf16)
  k_gemm_out<<<dim3(64, 8), 256, 0, stream>>>(ctx, wot, bo, yb, xb);

  k_ln<<<8192, 256, 0, stream>>>(yb, gamma, beta, out);
  (void)in_sizes; (void)n_in; (void)out_size; (void)ws_size;
}

// Round 15
// 175.040 us; speedup vs baseline: 1.0499x; 1.0499x over previous
//
#include <hip/hip_runtime.h>

typedef float f32x4 __attribute__((ext_vector_type(4)));
typedef float f32x16 __attribute__((ext_vector_type(16)));
typedef __bf16 bf16x8 __attribute__((ext_vector_type(8)));
typedef __bf16 bf16x4 __attribute__((ext_vector_type(4)));
typedef __bf16 bf16x2 __attribute__((ext_vector_type(2)));
typedef unsigned short us4 __attribute__((ext_vector_type(4)));

#define DEV __device__ __forceinline__

DEV unsigned short f2bf(float f) {
  union { float f; unsigned int u; } v; v.f = f;
  unsigned int u = v.u;
  return (unsigned short)((u + 0x7FFFu + ((u >> 16) & 1u)) >> 16);
}

typedef const __attribute__((address_space(1))) void* gvp;
typedef __attribute__((address_space(3))) void* lvp;

DEV void gll16(const void* g, void* l) {
  __builtin_amdgcn_global_load_lds((gvp)g, (lvp)l, 16, 0, 0);
}

DEV float fexp2(float x) { return __builtin_amdgcn_exp2f(x); }

DEV void plswap(unsigned& a, unsigned& b) {
  asm("v_permlane32_swap_b32 %0, %1" : "+v"(a), "+v"(b));
}
DEV float xhalf_sum(float v) {
  union { float f; unsigned u; } a, b;
  a.f = v; b.f = v;
  plswap(a.u, b.u);
  return a.f + b.f;
}

// ---------------- fused pre: convert fp32->bf16 (bid<8192) + 4x weight transpose ----------------
__global__ void k_pre(const float* __restrict__ x, unsigned short* __restrict__ xb,
                      const float* __restrict__ w0, const float* __restrict__ w1,
                      const float* __restrict__ w2, const float* __restrict__ w3,
                      unsigned short* __restrict__ o0, unsigned short* __restrict__ o1,
                      unsigned short* __restrict__ o2, unsigned short* __restrict__ o3) {
  __shared__ float tile[32][33];
  const int bid = blockIdx.x;
  const int tid = threadIdx.x;
  if (bid < 8192) {
    int i = bid * 256 + tid;
    float4 v = ((const float4*)x)[i];
    us4 o = { f2bf(v.x), f2bf(v.y), f2bf(v.z), f2bf(v.w) };
    ((us4*)xb)[i] = o;
    return;
  }
  int t = bid - 8192;
  const int z = t >> 10;
  t &= 1023;
  const float* in = (z == 0) ? w0 : (z == 1) ? w1 : (z == 2) ? w2 : w3;
  unsigned short* out = (z == 0) ? o0 : (z == 1) ? o1 : (z == 2) ? o2 : o3;
  const int bx = (t & 31) * 32, by = (t >> 5) * 32;
  const int tx = tid & 31, ty = tid >> 5;
#pragma unroll
  for (int r = 0; r < 4; ++r)
    tile[ty + r * 8][tx] = in[(size_t)(by + ty + r * 8) * 1024 + bx + tx];
  __syncthreads();
#pragma unroll
  for (int r = 0; r < 4; ++r)
    out[(size_t)(bx + ty + r * 8) * 1024 + by + tx] = f2bf(tile[tx][ty + r * 8]);
}

// ---------------- fused QKV projection GEMM (z: 0=q, 1=k, 2=v^T) ----------------
__global__ void k_gemm_qkv(const unsigned short* __restrict__ xb,
                           const unsigned short* __restrict__ wqt,
                           const unsigned short* __restrict__ wkt,
                           const unsigned short* __restrict__ wvt,
                           const float* __restrict__ bq, const float* __restrict__ bk,
                           const float* __restrict__ bv,
                           unsigned short* __restrict__ qb, unsigned short* __restrict__ kb,
                           unsigned short* __restrict__ vtb) {
  __shared__ unsigned short SM[2][128 * 64];
  unsigned short* As = SM[0];
  unsigned short* Bs = SM[1];
  const int tid = threadIdx.x;
  const int lane = tid & 63;
  const int wave = tid >> 6;
  const int l15 = lane & 15;
  const int lq  = lane >> 4;
  const int wm = wave >> 1, wn = wave & 1;
  const int z = blockIdx.z;

  const unsigned short* A;
  const unsigned short* Bt;
  int mbase, nbase;
  if (z == 2) { A = wvt; Bt = xb; mbase = blockIdx.y * 128; nbase = blockIdx.x * 128; }
  else        { A = xb; Bt = z ? wkt : wqt; mbase = blockIdx.x * 128; nbase = blockIdx.y * 128; }

  f32x4 acc[4][4] = {};

  for (int kt = 0; kt < 1024; kt += 64) {
    __syncthreads();
#pragma unroll
    for (int c = 0; c < 4; ++c) {
      int e = (c * 256 + tid) * 8;
      int row = e >> 6;
      int o2 = (e * 2) ^ ((row & 7) << 4);
      int col = (o2 >> 1) & 63;
      gll16(A + (size_t)(mbase + row) * 1024 + kt + col,
            As + (c * 256 + (tid & ~63)) * 8);
      gll16(Bt + (size_t)(nbase + row) * 1024 + kt + col,
            Bs + (c * 256 + (tid & ~63)) * 8);
    }
    __syncthreads();
#pragma unroll
    for (int ks = 0; ks < 2; ++ks) {
      bf16x8 af[4], bfv[4];
#pragma unroll
      for (int i = 0; i < 4; ++i) {
        int row = wm * 64 + i * 16 + l15;
        int off = row * 128 + ((((ks << 2) | lq) ^ (row & 7)) << 4);
        af[i] = *(const bf16x8*)((const char*)As + off);
      }
#pragma unroll
      for (int j = 0; j < 4; ++j) {
        int row = wn * 64 + j * 16 + l15;
        int off = row * 128 + ((((ks << 2) | lq) ^ (row & 7)) << 4);
        bfv[j] = *(const bf16x8*)((const char*)Bs + off);
      }
      // swapped operands: C^T fragment -> mi = l15 (lane axis), nj = lq*4+r (reg axis)
#pragma unroll
      for (int i = 0; i < 4; ++i)
#pragma unroll
        for (int j = 0; j < 4; ++j)
          acc[i][j] = __builtin_amdgcn_mfma_f32_16x16x32_bf16(bfv[j], af[i], acc[i][j], 0, 0, 0);
    }
  }

  const float scale = (z == 0) ? 0.18033688011112042f : 1.0f;
  const float* bias = (z == 0) ? bq : (z == 1) ? bk : bv;
  unsigned short* outp = (z == 0) ? qb : (z == 1) ? kb : vtb;

  float4 bj[4];
  if (z < 2) {
#pragma unroll
    for (int j = 0; j < 4; ++j)
      bj[j] = *(const float4*)&bias[nbase + wn * 64 + j * 16 + lq * 4];
  }

  __syncthreads();
  char* T = (char*)SM;
#pragma unroll
  for (int i = 0; i < 4; ++i) {
    const int miL = wm * 64 + i * 16 + l15;
    const int sw = (miL & 7) << 4;
    const float bm = (z == 2) ? bias[mbase + miL] : 0.f;
#pragma unroll
    for (int j = 0; j < 4; ++j) {
      const int nj2 = (wn * 64 + j * 16 + lq * 4) * 2;
      bf16x4 p;
#pragma unroll
      for (int r = 0; r < 4; ++r) {
        float v = acc[i][j][r];
        v = (z < 2) ? (v + ((const float*)&bj[j])[r]) * scale : (v + bm);
        p[r] = (__bf16)v;
      }
      *(bf16x4*)(T + miL * 256 + (nj2 ^ sw)) = p;
    }
  }
  __syncthreads();

#pragma unroll
  for (int c = 0; c < 8; ++c) {
    const int lin = c * 256 + tid;
    const int row = lin >> 4;
    const int s16 = lin & 15;
    bf16x8 vv = *(const bf16x8*)(T + row * 256 + ((s16 * 16) ^ ((row & 7) << 4)));
    const int mi = mbase + row;
    const int nj = nbase + s16 * 8;
    size_t gaddr;
    if (z < 2) {
      gaddr = (((size_t)((mi >> 11) * 16 + (nj >> 6)) * 2048 + (mi & 2047)) << 6) + (nj & 63);
    } else {
      gaddr = ((size_t)(((nj >> 11) * 16 + (mi >> 6)) * 64 + (mi & 63))) * 2048 + (nj & 2047);
    }
    *(bf16x8*)(outp + gaddr) = vv;
  }
}

// ---------------- output-projection GEMM: y(bf16) = ctx*Wo + bo + x ----------------
__global__ void k_gemm_out(const unsigned short* __restrict__ A,    // ctx
                           const unsigned short* __restrict__ Bt,   // wot
                           const float* __restrict__ bias,
                           unsigned short* __restrict__ yb,         // bf16 y out
                           const unsigned short* __restrict__ xres) { // xb residual
  __shared__ unsigned short SMo[2][128 * 64];
  unsigned short* As = SMo[0];
  unsigned short* Bs = SMo[1];
  const int tid = threadIdx.x;
  const int lane = tid & 63;
  const int wave = tid >> 6;
  const int l15 = lane & 15;
  const int lq  = lane >> 4;
  const int wm = wave >> 1, wn = wave & 1;
  const int mbase = blockIdx.x * 128;
  const int nbase = blockIdx.y * 128;

  f32x4 acc[4][4] = {};

  for (int kt = 0; kt < 1024; kt += 64) {
    __syncthreads();
#pragma unroll
    for (int c = 0; c < 4; ++c) {
      int e = (c * 256 + tid) * 8;
      int row = e >> 6;
      int o2 = (e * 2) ^ ((row & 7) << 4);
      int col = (o2 >> 1) & 63;
      gll16(A + (size_t)(mbase + row) * 1024 + kt + col,
            As + (c * 256 + (tid & ~63)) * 8);
      gll16(Bt + (size_t)(nbase + row) * 1024 + kt + col,
            Bs + (c * 256 + (tid & ~63)) * 8);
    }
    __syncthreads();
#pragma unroll
    for (int ks = 0; ks < 2; ++ks) {
      bf16x8 af[4], bfv[4];
#pragma unroll
      for (int i = 0; i < 4; ++i) {
        int row = wm * 64 + i * 16 + l15;
        int off = row * 128 + ((((ks << 2) | lq) ^ (row & 7)) << 4);
        af[i] = *(const bf16x8*)((const char*)As + off);
      }
#pragma unroll
      for (int j = 0; j < 4; ++j) {
        int row = wn * 64 + j * 16 + l15;
        int off = row * 128 + ((((ks << 2) | lq) ^ (row & 7)) << 4);
        bfv[j] = *(const bf16x8*)((const char*)Bs + off);
      }
#pragma unroll
      for (int i = 0; i < 4; ++i)
#pragma unroll
        for (int j = 0; j < 4; ++j)
          acc[i][j] = __builtin_amdgcn_mfma_f32_16x16x32_bf16(bfv[j], af[i], acc[i][j], 0, 0, 0);
    }
  }

  float4 bj[4];
#pragma unroll
  for (int j = 0; j < 4; ++j)
    bj[j] = *(const float4*)&bias[nbase + wn * 64 + j * 16 + lq * 4];

  __syncthreads();
  char* T = (char*)SMo;
#pragma unroll
  for (int i = 0; i < 4; ++i) {
    const int miL = wm * 64 + i * 16 + l15;
    const int sw = (miL & 7) << 4;
#pragma unroll
    for (int j = 0; j < 4; ++j) {
      const int nj2 = (wn * 64 + j * 16 + lq * 4) * 2;
      bf16x4 p;
#pragma unroll
      for (int r = 0; r < 4; ++r)
        p[r] = (__bf16)(acc[i][j][r] + ((const float*)&bj[j])[r]);
      *(bf16x4*)(T + miL * 256 + (nj2 ^ sw)) = p;
    }
  }
  __syncthreads();

#pragma unroll
  for (int c = 0; c < 8; ++c) {
    const int lin = c * 256 + tid;
    const int row = lin >> 4;
    const int s16 = lin & 15;
    bf16x8 vv = *(const bf16x8*)(T + row * 256 + ((s16 * 16) ^ ((row & 7) << 4)));
    const size_t g = (size_t)(mbase + row) * 1024 + nbase + s16 * 8;
    bf16x8 xv = *(const bf16x8*)(xres + g);
    bf16x8 ov;
#pragma unroll
    for (int e = 0; e < 8; ++e)
      ov[e] = (__bf16)((float)vv[e] + (float)xv[e]);
    *(bf16x8*)(yb + g) = ov;
  }
}

// ---------------- flash attention v10: [32][256B] pair-interleaved LDS tiles ----------------
// q,k: [B,H,S,64] bf16 (q pre-scaled by 0.125*log2e); vt: [B,H,64,S] bf16
// ctx out: [B,S,H,64] bf16.  QBLK=128, 4 waves x 32 q, KVBLK=64, 32x32x16 mfma.
__global__ __launch_bounds__(256, 4) void k_attn(const unsigned short* __restrict__ q,
                       const unsigned short* __restrict__ k,
                       const unsigned short* __restrict__ vt,
                       unsigned short* __restrict__ ctx) {
  __shared__ unsigned short KV[2][2][64 * 64];   // [buf][K|V^T], 32 KB

  const int tid = threadIdx.x;
  const int lane = tid & 63;
  const int wave = tid >> 6;
  const int l31 = lane & 31;
  const int l5 = lane >> 5;
  const int prl = l31 >> 1;            // 0..15
  const int b3  = (l31 & 1) << 3;

  const int bid = blockIdx.x;
  const int swz = (bid & 7) * 128 + (bid >> 3);
  const int bh = swz >> 4;
  const int qtile = swz & 15;
  const int qbase = qtile * 128;
  const size_t sl = (size_t)bh << 17;

  const int qrow = qbase + wave * 32 + l31;
  bf16x8 qreg[4];
#pragma unroll
  for (int ds = 0; ds < 4; ++ds)
    qreg[ds] = *(const bf16x8*)(q + sl + (size_t)qrow * 64 + ds * 16 + l5 * 8);

  // inverse-swizzled staging for the [32][256B] layout (rule 21)
#define STAGE_KV(BUF, TT) do {                                                 \
    const int kvb_ = (TT) * 64;                                                \
    _Pragma("unroll")                                                          \
    for (int c = 0; c < 2; ++c) {                                              \
      int ci = c * 256 + tid;                                                  \
      int pr_ = ci >> 4;                                                       \
      int u_ = (ci & 15) ^ (pr_ & 15);                                         \
      int lrow_ = pr_ * 2 + (u_ >> 3);                                         \
      int lc_ = u_ & 7;                                                        \
      gll16(k + sl + (size_t)(kvb_ + lrow_) * 64 + lc_ * 8,                    \
            KV[BUF][0] + (c * 256 + (tid & ~63)) * 8);                         \
      gll16(vt + sl + (size_t)lrow_ * 2048 + kvb_ + lc_ * 8,                   \
            KV[BUF][1] + (c * 256 + (tid & ~63)) * 8);                         \
    }                                                                          \
  } while (0)

  STAGE_KV(0, 0);
  __syncthreads();

  f32x16 acc0 = {}, acc1 = {};
  float lrow = 0.f;

  for (int t = 0; t < 32; ++t) {
    const int cur = t & 1;
    if (t < 31) STAGE_KV(cur ^ 1, t + 1);

    const char* Ksc = (const char*)KV[cur][0];
    const char* Vtc = (const char*)KV[cur][1];

    // ---- phase 1: K fragments + QK^T
    bf16x8 kf0[4], kf1[4];
#pragma unroll
    for (int ds = 0; ds < 4; ++ds) {
      int sc = (b3 | (2 * ds + l5)) ^ prl;
      kf0[ds] = *(const bf16x8*)(Ksc + prl * 256 + sc * 16);
      kf1[ds] = *(const bf16x8*)(Ksc + 4096 + prl * 256 + sc * 16);
    }
    f32x16 s0 = {}, s1 = {};
    __builtin_amdgcn_s_setprio(1);
#pragma unroll
    for (int ds = 0; ds < 4; ++ds)
      s0 = __builtin_amdgcn_mfma_f32_32x32x16_bf16(kf0[ds], qreg[ds], s0, 0, 0, 0);
#pragma unroll
    for (int ds = 0; ds < 4; ++ds)
      s1 = __builtin_amdgcn_mfma_f32_32x32x16_bf16(kf1[ds], qreg[ds], s1, 0, 0, 0);
    __builtin_amdgcn_s_setprio(0);
    __builtin_amdgcn_sched_barrier(0);

    // ---- phase 2: softmax (no max tracking)
    unsigned pk0[8], pk1[8];
    float r0s = 0.f, r1s = 0.f, r2s = 0.f, r3s = 0.f;
#pragma unroll
    for (int m = 0; m < 8; ++m) {
      float a0 = fexp2(s0[2 * m]), a1 = fexp2(s0[2 * m + 1]);
      float b0 = fexp2(s1[2 * m]), b1 = fexp2(s1[2 * m + 1]);
      r0s += a0; r1s += a1; r2s += b0; r3s += b1;
      union { bf16x2 v; unsigned u; } ua, ub;
      ua.v = bf16x2{ (__bf16)a0, (__bf16)a1 };
      ub.v = bf16x2{ (__bf16)b0, (__bf16)b1 };
      pk0[m] = ua.u; pk1[m] = ub.u;
    }
    lrow += (r0s + r1s) + (r2s + r3s);
    __builtin_amdgcn_sched_barrier(0);

    // ---- phase 3: V fragments + PV
    bf16x8 av0[4], av1[4];
#pragma unroll
    for (int kvg = 0; kvg < 4; ++kvg) {
      int sc = (b3 | (2 * kvg + l5)) ^ prl;
      av0[kvg] = *(const bf16x8*)(Vtc + prl * 256 + sc * 16);
      av1[kvg] = *(const bf16x8*)(Vtc + 4096 + prl * 256 + sc * 16);
    }
    __builtin_amdgcn_s_setprio(1);
#pragma unroll
    for (int kvh = 0; kvh < 2; ++kvh) {
      unsigned* pk = kvh ? pk1 : pk0;
#pragma unroll
      for (int g = 0; g < 2; ++g) {
        unsigned a0_ = pk[4 * g],     b0_ = pk[4 * g + 2];
        unsigned a1_ = pk[4 * g + 1], b1_ = pk[4 * g + 3];
        plswap(a0_, b0_);
        plswap(a1_, b1_);
        union { unsigned u[4]; bf16x8 v; } pf;
        pf.u[0] = a0_; pf.u[1] = a1_; pf.u[2] = b0_; pf.u[3] = b1_;
        const int kvg = 2 * kvh + g;
        acc0 = __builtin_amdgcn_mfma_f32_32x32x16_bf16(av0[kvg], pf.v, acc0, 0, 0, 0);
        acc1 = __builtin_amdgcn_mfma_f32_32x32x16_bf16(av1[kvg], pf.v, acc1, 0, 0, 0);
      }
    }
    __builtin_amdgcn_s_setprio(0);

    __syncthreads();
  }

  const float inv = 1.f / xhalf_sum(lrow);

  unsigned short* TR = (unsigned short*)KV;   // [128 q][64 d] epilogue scratch
  const int qloc = wave * 32 + l31;
  const int swq = (qloc & 7) << 4;
#pragma unroll
  for (int dh = 0; dh < 2; ++dh) {
    const f32x16& ac = dh ? acc1 : acc0;
#pragma unroll
    for (int g3 = 0; g3 < 4; ++g3) {
      bf16x4 o4 = { (__bf16)(ac[4 * g3] * inv), (__bf16)(ac[4 * g3 + 1] * inv),
                    (__bf16)(ac[4 * g3 + 2] * inv), (__bf16)(ac[4 * g3 + 3] * inv) };
      *(bf16x4*)((char*)TR + qloc * 128 + ((dh * 64 + g3 * 16 + l5 * 8) ^ swq)) = o4;
    }
  }
  __syncthreads();

  const int b = bh >> 4, h = bh & 15;
  {
    int row = tid >> 1, half = tid & 1;
    int sw = (row & 7) << 4;
    unsigned short* gdst = ctx + (size_t)(b * 2048 + qbase + row) * 1024 + h * 64 + half * 32;
#pragma unroll
    for (int i = 0; i < 4; ++i) {
      bf16x8 vv = *(const bf16x8*)((const char*)TR + row * 128 + ((half * 64 + i * 16) ^ sw));
      *(bf16x8*)(gdst + i * 8) = vv;
    }
  }
#undef STAGE_KV
}

// ---------------- LayerNorm over D=1024, bf16 input ----------------
__global__ void k_ln(const unsigned short* __restrict__ y, const float* __restrict__ gamma,
                     const float* __restrict__ beta, float* __restrict__ out) {
  const int row = blockIdx.x;
  const int tid = threadIdx.x;
  const bf16x4 v4 = *(const bf16x4*)(y + (size_t)row * 1024 + tid * 4);
  float v0 = (float)v4[0], v1 = (float)v4[1], v2 = (float)v4[2], v3 = (float)v4[3];
  float sum = v0 + v1 + v2 + v3;
  float sq = v0 * v0 + v1 * v1 + v2 * v2 + v3 * v3;
#pragma unroll
  for (int m = 1; m <= 32; m <<= 1) {
    sum += __shfl_xor(sum, m);
    sq  += __shfl_xor(sq, m);
  }
  __shared__ float s1[4], s2[4];
  const int wv = tid >> 6, lane = tid & 63;
  if (lane == 0) { s1[wv] = sum; s2[wv] = sq; }
  __syncthreads();
  sum = s1[0] + s1[1] + s1[2] + s1[3];
  sq  = s2[0] + s2[1] + s2[2] + s2[3];
  const float mu = sum * (1.f / 1024.f);
  const float rs = rsqrtf(sq * (1.f / 1024.f) - mu * mu + 1e-3f);
  const float4 g  = ((const float4*)gamma)[tid];
  const float4 bb = ((const float4*)beta)[tid];
  float4 o;
  o.x = (v0 - mu) * rs * g.x + bb.x;
  o.y = (v1 - mu) * rs * g.y + bb.y;
  o.z = (v2 - mu) * rs * g.z + bb.z;
  o.w = (v3 - mu) * rs * g.w + bb.w;
  ((float4*)(out + (size_t)row * 1024))[tid] = o;
}

extern "C" void kernel_launch(void* const* d_in, const int* in_sizes, int n_in,
                              void* d_out, int out_size, void* d_ws, size_t ws_size,
                              hipStream_t stream) {
  const float* x  = (const float*)d_in[0];
  const float* Wq = (const float*)d_in[1];
  const float* bq = (const float*)d_in[2];
  const float* Wk = (const float*)d_in[3];
  const float* bk = (const float*)d_in[4];
  const float* Wv = (const float*)d_in[5];
  const float* bv = (const float*)d_in[6];
  const float* Wo = (const float*)d_in[7];
  const float* bo = (const float*)d_in[8];
  const float* gamma = (const float*)d_in[9];
  const float* beta  = (const float*)d_in[10];
  float* out = (float*)d_out;

  char* ws = (char*)d_ws;
  const size_t MB = 1024 * 1024;
  unsigned short* xb  = (unsigned short*)(ws);            // 16MB  x bf16 [8192][1024]
  unsigned short* wqt = (unsigned short*)(ws + 16 * MB);  // 2MB   Wq^T bf16
  unsigned short* wkt = (unsigned short*)(ws + 18 * MB);
  unsigned short* wvt = (unsigned short*)(ws + 20 * MB);
  unsigned short* wot = (unsigned short*)(ws + 22 * MB);
  unsigned short* qb  = (unsigned short*)(ws + 24 * MB);  // 16MB  q [B,H,S,64]
  unsigned short* kb  = (unsigned short*)(ws + 40 * MB);  // 16MB  k [B,H,S,64]
  unsigned short* vtb = (unsigned short*)(ws + 56 * MB);  // 16MB  v^T [B,H,64,S]
  unsigned short* ctx = (unsigned short*)(ws + 72 * MB);  // 16MB  ctx [B,S,H,64]
  unsigned short* yb  = (unsigned short*)(ws + 24 * MB);  // 16MB  y bf16, aliases qb (dead after attn)

  k_pre<<<12288, 256, 0, stream>>>(x, xb, Wq, Wk, Wv, Wo, wqt, wkt, wvt, wot);

  // q = (x Wq + bq)*0.125*log2e ; k = x Wk + bk ; v^T = Wv^T x^T — one launch
  k_gemm_qkv<<<dim3(64, 8, 3), 256, 0, stream>>>(xb, wqt, wkt, wvt, bq, bk, bv, qb, kb, vtb);

  k_attn<<<1024, 256, 0, stream>>>(qb, kb, vtb, ctx);

  // y = ctx Wo + bo + x  (bf16)
  k_gemm_out<<<dim3(64, 8), 256, 0, stream>>>(ctx, wot, bo, yb, xb);

  k_ln<<<8192, 256, 0, stream>>>(yb, gamma, beta, out);
  (void)in_sizes; (void)n_in; (void)out_size; (void)ws_size;
}